// Round 3
// baseline (137.215 us; speedup 1.0000x reference)
//
#include <hip/hip_runtime.h>

#define VOCAB 100000
#define EMB   128
#define BATCH 16384
#define NEGS  10

// 4 waves per block, each wave handles 2 batch elements -> 8 per block
#define WAVES_PER_BLOCK 4
#define ELEMS_PER_BLOCK (WAVES_PER_BLOCK * 2)
#define NBLOCKS (BATCH / ELEMS_PER_BLOCK)   // 2048, exact

__device__ __forceinline__ float log_sigmoid(float x) {
    // stable: min(x,0) - log1p(exp(-|x|))
    return fminf(x, 0.0f) - log1pf(expf(-fabsf(x)));
}

__global__ __launch_bounds__(256) void w2v_fwd(
    const float* __restrict__ iemb_w,
    const float* __restrict__ oemb_w,
    const int*   __restrict__ iwords,
    const int*   __restrict__ owords,
    const int*   __restrict__ negwords,
    float*       __restrict__ out)
{
    const int lane = threadIdx.x & 63;
    const int wid  = threadIdx.x >> 6;                 // 0..3
    const int b0   = (blockIdx.x * WAVES_PER_BLOCK + wid) * 2;
    const int b1   = b0 + 1;

    // Each lane owns 2 consecutive floats of each 128-float row.
    const float2* i0 = (const float2*)(iemb_w + (size_t)iwords[b0] * EMB);
    const float2* o0 = (const float2*)(oemb_w + (size_t)owords[b0] * EMB);
    const float2* i1 = (const float2*)(iemb_w + (size_t)iwords[b1] * EMB);
    const float2* o1 = (const float2*)(oemb_w + (size_t)owords[b1] * EMB);

    float2 iv0 = i0[lane], ov0 = o0[lane];
    float2 iv1 = i1[lane], ov1 = o1[lane];

    float pos0 = iv0.x * ov0.x + iv0.y * ov0.y;
    float pos1 = iv1.x * ov1.x + iv1.y * ov1.y;

    // Sum the negative rows elementwise (interleaved for MLP), then one dot each.
    float2 ns0 = make_float2(0.f, 0.f);
    float2 ns1 = make_float2(0.f, 0.f);
    #pragma unroll
    for (int k = 0; k < NEGS; ++k) {
        const float2* n0 =
            (const float2*)(oemb_w + (size_t)negwords[b0 * NEGS + k] * EMB);
        const float2* n1 =
            (const float2*)(oemb_w + (size_t)negwords[b1 * NEGS + k] * EMB);
        float2 a = n0[lane];
        float2 b = n1[lane];
        ns0.x += a.x; ns0.y += a.y;
        ns1.x += b.x; ns1.y += b.y;
    }
    float neg0 = iv0.x * ns0.x + iv0.y * ns0.y;
    float neg1 = iv1.x * ns1.x + iv1.y * ns1.y;

    // Wave reduce all four dots (6 butterfly steps over 64 lanes).
    #pragma unroll
    for (int s = 32; s; s >>= 1) {
        pos0 += __shfl_xor(pos0, s);
        neg0 += __shfl_xor(neg0, s);
        pos1 += __shfl_xor(pos1, s);
        neg1 += __shfl_xor(neg1, s);
    }

    float val = 0.f;
    if (lane == 0)
        val = -(log_sigmoid(pos0) + log_sigmoid(-neg0))
            - (log_sigmoid(pos1) + log_sigmoid(-neg1));

    // Block reduce the 4 wave-leader values, one atomic per block.
    __shared__ float sm[WAVES_PER_BLOCK];
    if (lane == 0) sm[wid] = val;
    __syncthreads();
    if (threadIdx.x == 0)
        atomicAdd(out, sm[0] + sm[1] + sm[2] + sm[3]);
}

extern "C" void kernel_launch(void* const* d_in, const int* in_sizes, int n_in,
                              void* d_out, int out_size, void* d_ws, size_t ws_size,
                              hipStream_t stream) {
    const float* iemb_w   = (const float*)d_in[0];
    const float* oemb_w   = (const float*)d_in[1];
    const int*   iwords   = (const int*)d_in[2];
    const int*   owords   = (const int*)d_in[3];
    const int*   negwords = (const int*)d_in[4];
    float* out = (float*)d_out;

    // d_out is poisoned 0xAA before every timed launch -> zero it (capture-safe).
    hipMemsetAsync(out, 0, sizeof(float), stream);

    w2v_fwd<<<NBLOCKS, 256, 0, stream>>>(iemb_w, oemb_w, iwords, owords,
                                         negwords, out);
}

// Round 14
// 121.197 us; speedup vs baseline: 1.1322x; 1.1322x over previous
//
#include <hip/hip_runtime.h>

#define EMB   128
#define BATCH 16384
#define NEGS  10

// 4 waves per block; each wave handles 2 batch elements (one per 32-lane half).
// A 512B row = 32 lanes x float4.
#define WAVES_PER_BLOCK 4
#define ELEMS_PER_BLOCK (WAVES_PER_BLOCK * 2)
#define NBLOCKS (BATCH / ELEMS_PER_BLOCK)   // 2048, exact

__device__ __forceinline__ float log_sigmoid(float x) {
    // stable: min(x,0) - log1p(exp(-|x|))
    return fminf(x, 0.0f) - log1pf(expf(-fabsf(x)));
}

__global__ __launch_bounds__(256) void w2v_fwd(
    const float* __restrict__ iemb_w,
    const float* __restrict__ oemb_w,
    const int*   __restrict__ iwords,
    const int*   __restrict__ owords,
    const int*   __restrict__ negwords,
    float*       __restrict__ partial)
{
    const int lane = threadIdx.x & 63;
    const int wid  = threadIdx.x >> 6;      // 0..3
    const int half = lane >> 5;             // 0 or 1 -> which batch element
    const int sub  = lane & 31;             // lane within the 32-lane half
    const int b    = (blockIdx.x * WAVES_PER_BLOCK + wid) * 2 + half;

    const float4* irow = (const float4*)(iemb_w + (size_t)iwords[b] * EMB);
    const float4* orow = (const float4*)(oemb_w + (size_t)owords[b] * EMB);
    float4 iv = irow[sub];
    float4 ov = orow[sub];
    float pos = iv.x * ov.x + iv.y * ov.y + iv.z * ov.z + iv.w * ov.w;

    // Elementwise-sum the 10 negative rows, then one dot with iemb
    // (valid because the reference sums neg_scores over K before log_sigmoid).
    float4 ns = make_float4(0.f, 0.f, 0.f, 0.f);
    #pragma unroll
    for (int k = 0; k < NEGS; ++k) {
        const float4* nrow =
            (const float4*)(oemb_w + (size_t)negwords[b * NEGS + k] * EMB);
        float4 nv = nrow[sub];
        ns.x += nv.x; ns.y += nv.y; ns.z += nv.z; ns.w += nv.w;
    }
    float neg = iv.x * ns.x + iv.y * ns.y + iv.z * ns.z + iv.w * ns.w;

    // Reduce within each 32-lane half (xor masks <32 never cross halves).
    #pragma unroll
    for (int s = 16; s; s >>= 1) {
        pos += __shfl_xor(pos, s);
        neg += __shfl_xor(neg, s);
    }
    // lane 0 holds element b0's sums, lane 32 holds b1's.

    __shared__ float sm[ELEMS_PER_BLOCK];
    if (sub == 0)
        sm[wid * 2 + half] = -(log_sigmoid(pos) + log_sigmoid(-neg));
    __syncthreads();
    if (threadIdx.x == 0) {
        float t = 0.f;
        #pragma unroll
        for (int i = 0; i < ELEMS_PER_BLOCK; ++i) t += sm[i];
        partial[blockIdx.x] = t;     // deterministic: no atomics
    }
}

__global__ __launch_bounds__(1024) void w2v_reduce(
    const float* __restrict__ partial, float* __restrict__ out)
{
    float v = 0.f;
    #pragma unroll
    for (int i = 0; i < NBLOCKS / 1024; ++i)
        v += partial[threadIdx.x + i * 1024];
    #pragma unroll
    for (int s = 32; s; s >>= 1) v += __shfl_xor(v, s);
    __shared__ float sm[16];
    const int lane = threadIdx.x & 63, wid = threadIdx.x >> 6;
    if (lane == 0) sm[wid] = v;
    __syncthreads();
    if (threadIdx.x == 0) {
        float t = 0.f;
        #pragma unroll
        for (int i = 0; i < 16; ++i) t += sm[i];
        *out = t;
    }
}

extern "C" void kernel_launch(void* const* d_in, const int* in_sizes, int n_in,
                              void* d_out, int out_size, void* d_ws, size_t ws_size,
                              hipStream_t stream) {
    const float* iemb_w   = (const float*)d_in[0];
    const float* oemb_w   = (const float*)d_in[1];
    const int*   iwords   = (const int*)d_in[2];
    const int*   owords   = (const int*)d_in[3];
    const int*   negwords = (const int*)d_in[4];
    float* out     = (float*)d_out;
    float* partial = (float*)d_ws;   // NBLOCKS floats = 8 KiB

    w2v_fwd<<<NBLOCKS, 256, 0, stream>>>(iemb_w, oemb_w, iwords, owords,
                                         negwords, partial);
    w2v_reduce<<<1, 1024, 0, stream>>>(partial, out);
}